// Round 18
// baseline (307.792 us; speedup 1.0000x reference)
//
#include <hip/hip_runtime.h>

#define NTOK 262144   // 64*64*64 tokens per batch
#define NCH  64
#define NB   4

// ws layout (floats): S[4][4] @0, m[4][4][64] @16, rc[4][64] @1040
#define WS_S  0
#define WS_M  16
#define WS_RC 1040

typedef float floatx4 __attribute__((ext_vector_type(4)));   // native vec for nontemporal

// ---------- K1: partial keys, 16 channels per block ----------
// kpart[b][g][n][4heads] fp32. Streams/block = 16 reads + 1 write; all reads
// 4KB-extent per channel per step. Same-set (1MB-strided) concurrency <= 16.
__global__ __launch_bounds__(256)
void ea3d_kpart(const float* __restrict__ x, const float* __restrict__ Wk,
                float* __restrict__ kp)
{
    __shared__ __align__(16) float wk4[16 * 4];   // this group's Wk, [c][h]
    const int tid = threadIdx.x;
    const int g   = blockIdx.y;
    const int b   = blockIdx.z;
    if (tid < 64) { int c = tid >> 2, h = tid & 3; wk4[(c << 2) + h] = Wk[h * NCH + (g * 16 + c)]; }
    __syncthreads();

    const float*  xb  = x + ((size_t)b * NCH + g * 16) * NTOK;
    float4*       kpb = (float4*)kp + ((size_t)(b * 4 + g)) * NTOK;

    #pragma unroll 1
    for (int s = 0; s < 4; ++s) {
        const int n = blockIdx.x * 4096 + s * 1024 + tid * 4;
        float k[16];                       // k[h*4 + j]
        #pragma unroll
        for (int r = 0; r < 16; ++r) k[r] = 0.f;
        #pragma unroll
        for (int c = 0; c < 16; ++c) {
            float4 xv = *(const float4*)(xb + (size_t)c * NTOK + n);
            float4 wv = *((const float4*)wk4 + c);
            k[0]  += wv.x * xv.x; k[1]  += wv.x * xv.y; k[2]  += wv.x * xv.z; k[3]  += wv.x * xv.w;
            k[4]  += wv.y * xv.x; k[5]  += wv.y * xv.y; k[6]  += wv.y * xv.z; k[7]  += wv.y * xv.w;
            k[8]  += wv.z * xv.x; k[9]  += wv.z * xv.y; k[10] += wv.z * xv.z; k[11] += wv.z * xv.w;
            k[12] += wv.w * xv.x; k[13] += wv.w * xv.y; k[14] += wv.w * xv.z; k[15] += wv.w * xv.w;
        }
        // token-major: token n+j -> float4(h0..h3); 64B contiguous per thread
        kpb[n + 0] = make_float4(k[0], k[4], k[8],  k[12]);
        kpb[n + 1] = make_float4(k[1], k[5], k[9],  k[13]);
        kpb[n + 2] = make_float4(k[2], k[6], k[10], k[14]);
        kpb[n + 3] = make_float4(k[3], k[7], k[11], k[15]);
    }
}

// ---------- K2: combine 4 group-partials -> e (token-major) + S ----------
__global__ __launch_bounds__(256)
void ea3d_combine(const float* __restrict__ kp, float* __restrict__ e,
                  float* __restrict__ ws)
{
    __shared__ float ssum[4][4];
    const int tid = threadIdx.x;
    const int w   = tid >> 6;
    const int b   = blockIdx.y;
    const size_t n0 = (size_t)blockIdx.x * 1024 + tid * 4;

    const float4* kp0 = (const float4*)kp + ((size_t)(b * 4 + 0)) * NTOK + n0;
    const float4* kp1 = (const float4*)kp + ((size_t)(b * 4 + 1)) * NTOK + n0;
    const float4* kp2 = (const float4*)kp + ((size_t)(b * 4 + 2)) * NTOK + n0;
    const float4* kp3 = (const float4*)kp + ((size_t)(b * 4 + 3)) * NTOK + n0;
    float4* eb = (float4*)e + (size_t)b * NTOK + n0;

    float sacc[4] = {0.f, 0.f, 0.f, 0.f};
    #pragma unroll
    for (int j = 0; j < 4; ++j) {
        float4 a = kp0[j], b1 = kp1[j], c = kp2[j], d = kp3[j];
        float4 ev;
        ev.x = __expf(a.x + b1.x + c.x + d.x);
        ev.y = __expf(a.y + b1.y + c.y + d.y);
        ev.z = __expf(a.z + b1.z + c.z + d.z);
        ev.w = __expf(a.w + b1.w + c.w + d.w);
        eb[j] = ev;
        sacc[0] += ev.x; sacc[1] += ev.y; sacc[2] += ev.z; sacc[3] += ev.w;
    }
    #pragma unroll
    for (int h = 0; h < 4; ++h) {
        float v = sacc[h];
        #pragma unroll
        for (int off = 32; off; off >>= 1) v += __shfl_xor(v, off);
        sacc[h] = v;
    }
    if ((tid & 63) == 0) { ssum[w][0] = sacc[0]; ssum[w][1] = sacc[1]; ssum[w][2] = sacc[2]; ssum[w][3] = sacc[3]; }
    __syncthreads();
    if (tid < 4) {
        float s = (ssum[0][tid] + ssum[1][tid]) + (ssum[2][tid] + ssum[3][tid]);
        __hip_atomic_fetch_add(ws + WS_S + b * 4 + tid, s,
                               __ATOMIC_RELAXED, __HIP_MEMORY_SCOPE_AGENT);
    }
}

// ---------- K3: m[h][c] = sum_n e[h][n]*x[c][n]; 8 channels per block ----------
__global__ __launch_bounds__(256)
void ea3d_msum(const float* __restrict__ x, const float* __restrict__ e,
               float* __restrict__ ws)
{
    const int tid = threadIdx.x;
    const int b   = blockIdx.z;
    const int c0  = blockIdx.y << 3;
    const float*  xb = x + ((size_t)b * NCH + c0) * NTOK;
    const float4* eb = (const float4*)e + (size_t)b * NTOK;

    float macc[32];                    // macc[c*4 + h] — static only
    #pragma unroll
    for (int r = 0; r < 32; ++r) macc[r] = 0.f;

    #pragma unroll 1
    for (int s = 0; s < 8; ++s) {
        const size_t n = (size_t)blockIdx.x * 8192 + s * 1024 + tid * 4;
        float4 e0 = eb[n + 0], e1 = eb[n + 1], e2 = eb[n + 2], e3 = eb[n + 3];
        #pragma unroll
        for (int c = 0; c < 8; ++c) {
            float4 xv = *(const float4*)(xb + (size_t)c * NTOK + n);
            macc[c*4+0] += e0.x*xv.x + e1.x*xv.y + e2.x*xv.z + e3.x*xv.w;
            macc[c*4+1] += e0.y*xv.x + e1.y*xv.y + e2.y*xv.z + e3.y*xv.w;
            macc[c*4+2] += e0.z*xv.x + e1.z*xv.y + e2.z*xv.z + e3.z*xv.w;
            macc[c*4+3] += e0.w*xv.x + e1.w*xv.y + e2.w*xv.z + e3.w*xv.w;
        }
    }

    #pragma unroll
    for (int r = 0; r < 32; ++r) {
        float v = macc[r];
        v += __shfl_xor(v, 1);  v += __shfl_xor(v, 2);
        v += __shfl_xor(v, 4);  v += __shfl_xor(v, 8);
        v += __shfl_xor(v, 16); v += __shfl_xor(v, 32);
        macc[r] = v;
    }
    if ((tid & 63) == 0) {             // one lane per wave: 32 atomics
        float* mb = ws + WS_M + (size_t)(b * 4) * NCH + c0;
        #pragma unroll
        for (int c = 0; c < 8; ++c) {
            #pragma unroll
            for (int h = 0; h < 4; ++h)
                __hip_atomic_fetch_add(mb + h * NCH + c, macc[c*4+h],
                                       __ATOMIC_RELAXED, __HIP_MEMORY_SCOPE_AGENT);
        }
    }
}

// ---------- finalize: context = Wv*(m/S)+bv ; rc = Wr*context + br ----------
__global__ void ea3d_finalize(const float* __restrict__ Wv, const float* __restrict__ bv,
                              const float* __restrict__ Wr, const float* __restrict__ br,
                              float* __restrict__ ws)
{
    __shared__ float ctx[NB * 32];
    const int tid = threadIdx.x;
    if (tid < 128) {
        int b = tid >> 5, hv = tid & 31, h = hv >> 3;
        float inv = 1.0f / ws[WS_S + b * 4 + h];
        const float* m = ws + WS_M + (b * 4 + h) * NCH;
        const float* wvr = Wv + hv * NCH;
        float acc = 0.f;
        #pragma unroll
        for (int c = 0; c < NCH; ++c) acc += wvr[c] * m[c];
        ctx[b * 32 + hv] = acc * inv + bv[hv];
    }
    __syncthreads();
    int b = tid >> 6, c = tid & 63;
    const float* wrr = Wr + c * 32;
    const float* cb  = ctx + b * 32;
    float acc = br[c];
    #pragma unroll
    for (int hv = 0; hv < 32; ++hv) acc += wrr[hv] * cb[hv];
    ws[WS_RC + b * NCH + c] = acc;
}

// ---------- out = x + rc[b][c]  (nontemporal stores) ----------
__global__ __launch_bounds__(256)
void ea3d_add(const float* __restrict__ x, const float* __restrict__ ws,
              float* __restrict__ out)
{
    const int row = blockIdx.y;                 // b*64 + c
    const float rc = ws[WS_RC + row];
    const size_t base = (size_t)row * NTOK;
    const float4*  xp = (const float4*)(x + base);
    floatx4*       op = (floatx4*)(out + base);
    const int nvec = NTOK / 4;
    for (int i = blockIdx.x * blockDim.x + threadIdx.x; i < nvec;
         i += gridDim.x * blockDim.x) {
        float4 v = xp[i];
        floatx4 nv = { v.x + rc, v.y + rc, v.z + rc, v.w + rc };
        __builtin_nontemporal_store(nv, op + i);
    }
}

extern "C" void kernel_launch(void* const* d_in, const int* in_sizes, int n_in,
                              void* d_out, int out_size, void* d_ws, size_t ws_size,
                              hipStream_t stream)
{
    const float* x  = (const float*)d_in[0];
    const float* Wk = (const float*)d_in[1];
    // d_in[2]=bk (cancels in token-softmax); d_in[3]=Wq, d_in[4]=bq (softmax over
    // size-1 head-channel axis -> identically 1.0, so Wq/bq are dead)
    const float* Wv = (const float*)d_in[5];
    const float* bv = (const float*)d_in[6];
    const float* Wr = (const float*)d_in[7];
    const float* br = (const float*)d_in[8];
    float* out = (float*)d_out;
    float* ws  = (float*)d_ws;

    // scratch in d_out (overwritten by ea3d_add at the end):
    // kpart[b][g][n][4] fp32 = 67MB @0 ; e[b][n][4] fp32 = 17MB after it
    float* kp = (float*)d_out;
    float* e  = (float*)d_out + (size_t)NB * 4 * NTOK * 4;

    (void)hipMemsetAsync(ws, 0, WS_RC * sizeof(float), stream);  // zero S + m accumulators
    ea3d_kpart  <<<dim3(NTOK / 4096, 4, NB), 256, 0, stream>>>(x, Wk, kp);
    ea3d_combine<<<dim3(NTOK / 1024, NB),    256, 0, stream>>>(kp, e, ws);
    ea3d_msum   <<<dim3(NTOK / 8192, 8, NB), 256, 0, stream>>>(x, e, ws);
    ea3d_finalize<<<1, 256, 0, stream>>>(Wv, bv, Wr, br, ws);
    ea3d_add    <<<dim3(32, NB * NCH), 256, 0, stream>>>(x, ws, out);
}

// Round 19
// 164.524 us; speedup vs baseline: 1.8708x; 1.8708x over previous
//
#include <hip/hip_runtime.h>

#define NTOK 262144   // 64*64*64 tokens per batch
#define NCH  64
#define NB   4

#define TPB   512     // 8 waves
#define TILE  512     // tokens per tile; channel row = 2KB (2 consecutive 1KB DMA chunks)
#define GRIDX 64      // blocks per batch -> 256 total = 1/CU
#define NIT   (NTOK / (GRIDX * TILE))   // 8 tiles per block

// ws layout (floats): S[4][4] @0, m[4][4][64] @16, rc[4][64] @1040
#define WS_S  0
#define WS_M  16
#define WS_RC 1040

typedef float floatx4 __attribute__((ext_vector_type(4)));   // native vec for nontemporal
typedef const __attribute__((address_space(1))) unsigned int* gas1p;
typedef __attribute__((address_space(3))) unsigned int*       las3p;

// Single-x-read fused reduce, 2KB DMA staging. This is the measured-best
// structure (r16: 164.8 us total). The gather pattern (64 channel rows at
// 1MB stride) is pinned at ~2.2-2.6 TB/s on this chip — invariant under
// extent, pipelining, occupancy, phase spread, stream count, and staging
// mechanism (6 pre-committed experiments, r11-r18) — so the kernel accepts
// the drain bubble (r15 proved pipelining is free but gains nothing) and
// keeps registers at ~70 VGPR (spill cliffs burned r5/r8/r9/r13).
__global__ __launch_bounds__(TPB)
void ea3d_reduce(const float* __restrict__ x, const float* __restrict__ Wk,
                 float* __restrict__ ws)
{
    __shared__ __align__(16) float buf[NCH][TILE];   // 128KB x-tile (single buffer)
    __shared__ __align__(16) float es2[4][TILE + 8]; // e, h-major (+pad)
    __shared__ __align__(16) float wk4[NCH][4];      // Wk transposed
    __shared__ float ssum[8][4];

    const int tid = threadIdx.x;
    const int w   = tid >> 6;
    const int l   = tid & 63;
    const int b   = blockIdx.y;

    if (tid < 256) wk4[tid >> 2][tid & 3] = Wk[(tid & 3) * NCH + (tid >> 2)];
    __syncthreads();

    const float* xb = x + (size_t)b * NCH * NTOK;
    const size_t tokblk = (size_t)blockIdx.x * (TILE * NIT);
    const int    c0 = w << 3;                 // wave stages / m-accumulates ch 8w..8w+8

    float macc[32];                           // macc[i*4+h], channel c0+i
    #pragma unroll
    for (int r = 0; r < 32; ++r) macc[r] = 0.f;
    float sacc[4] = {0.f, 0.f, 0.f, 0.f};

    // Stage one tile: per wave 8 channel rows, each as 2 consecutive 1KB DMA
    // chunks (lane-swept src; WAVE-UNIFORM LDS dst base, HW adds lane*16).
    auto stage = [&](int tt) {
        const size_t t0 = tokblk + (size_t)tt * TILE + (l << 2);
        #pragma unroll
        for (int i = 0; i < 8; ++i) {
            const float* src = xb + (size_t)(c0 + i) * NTOK + t0;
            __builtin_amdgcn_global_load_lds((gas1p)src,         (las3p)&buf[c0 + i][0],   16, 0, 0);
            __builtin_amdgcn_global_load_lds((gas1p)(src + 256), (las3p)&buf[c0 + i][256], 16, 0, 0);
        }
    };

    stage(0);                                 // prologue

    #pragma unroll 1
    for (int t = 0; t < NIT; ++t) {
        asm volatile("s_waitcnt vmcnt(0)" ::: "memory");   // this wave's DMAs landed
        __builtin_amdgcn_s_barrier();                      // B1: whole tile visible
        asm volatile("" ::: "memory");

        // ---- keys: thread tid -> token tk = tid, full 64-channel dot ----
        {
            const int tk = tid;
            float k0 = 0.f, k1 = 0.f, k2 = 0.f, k3 = 0.f;
            #pragma unroll 16
            for (int c = 0; c < NCH; ++c) {
                float  xv = buf[c][tk];
                float4 wv = *(const float4*)&wk4[c][0];   // uniform addr -> broadcast
                k0 += wv.x * xv; k1 += wv.y * xv; k2 += wv.z * xv; k3 += wv.w * xv;
            }
            float e0 = __expf(k0), e1 = __expf(k1), e2 = __expf(k2), e3 = __expf(k3);
            es2[0][tk] = e0; es2[1][tk] = e1; es2[2][tk] = e2; es2[3][tk] = e3;
            sacc[0] += e0; sacc[1] += e1; sacc[2] += e2; sacc[3] += e3;
        }

        asm volatile("s_waitcnt lgkmcnt(0)" ::: "memory");
        __builtin_amdgcn_s_barrier();                      // B2: es ready
        asm volatile("" ::: "memory");

        // ---- m-phase: wave's 8 channels, lane tokens {l+64s} (conflict-free) ----
        #pragma unroll
        for (int s = 0; s < 8; ++s) {
            const int tk = l + (s << 6);
            float e0 = es2[0][tk], e1 = es2[1][tk], e2 = es2[2][tk], e3 = es2[3][tk];
            #pragma unroll
            for (int i = 0; i < 8; ++i) {
                float xv = buf[c0 + i][tk];
                macc[i*4+0] += e0 * xv;
                macc[i*4+1] += e1 * xv;
                macc[i*4+2] += e2 * xv;
                macc[i*4+3] += e3 * xv;
            }
        }

        asm volatile("s_waitcnt lgkmcnt(0)" ::: "memory");
        __builtin_amdgcn_s_barrier();                      // B3: buf free for overwrite
        asm volatile("" ::: "memory");

        if (t + 1 < NIT) stage(t + 1);
    }

    // ---- macc: reduce over 64 lanes (token dim) -> 32 atomics per wave ----
    #pragma unroll
    for (int r = 0; r < 32; ++r) {
        float v = macc[r];
        v += __shfl_xor(v, 1);  v += __shfl_xor(v, 2);
        v += __shfl_xor(v, 4);  v += __shfl_xor(v, 8);
        v += __shfl_xor(v, 16); v += __shfl_xor(v, 32);
        macc[r] = v;
    }
    if (l == 0) {
        float* mb = ws + WS_M + (size_t)(b * 4) * NCH + c0;
        #pragma unroll
        for (int i = 0; i < 8; ++i) {
            #pragma unroll
            for (int h = 0; h < 4; ++h)
                __hip_atomic_fetch_add(mb + h * NCH + i, macc[i*4+h],
                                       __ATOMIC_RELAXED, __HIP_MEMORY_SCOPE_AGENT);
        }
    }

    // ---- S: every thread summed its own tokens; reduce wave -> block -> global ----
    {
        float v0 = sacc[0], v1 = sacc[1], v2 = sacc[2], v3 = sacc[3];
        #pragma unroll
        for (int off = 1; off < 64; off <<= 1) {
            v0 += __shfl_xor(v0, off); v1 += __shfl_xor(v1, off);
            v2 += __shfl_xor(v2, off); v3 += __shfl_xor(v3, off);
        }
        if (l == 0) { ssum[w][0] = v0; ssum[w][1] = v1; ssum[w][2] = v2; ssum[w][3] = v3; }
    }
    __syncthreads();
    if (tid < 4) {
        float s = 0.f;
        #pragma unroll
        for (int w2 = 0; w2 < 8; ++w2) s += ssum[w2][tid];
        __hip_atomic_fetch_add(ws + WS_S + b * 4 + tid, s,
                               __ATOMIC_RELAXED, __HIP_MEMORY_SCOPE_AGENT);
    }
}

// ---------- finalize: context = Wv*(m/S)+bv ; rc = Wr*context + br ----------
__global__ void ea3d_finalize(const float* __restrict__ Wv, const float* __restrict__ bv,
                              const float* __restrict__ Wr, const float* __restrict__ br,
                              float* __restrict__ ws)
{
    __shared__ float ctx[NB * 32];
    const int tid = threadIdx.x;
    if (tid < 128) {
        int b = tid >> 5, hv = tid & 31, h = hv >> 3;
        float inv = 1.0f / ws[WS_S + b * 4 + h];
        const float* m = ws + WS_M + (b * 4 + h) * NCH;
        const float* wvr = Wv + hv * NCH;
        float acc = 0.f;
        #pragma unroll
        for (int c = 0; c < NCH; ++c) acc += wvr[c] * m[c];
        ctx[b * 32 + hv] = acc * inv + bv[hv];
    }
    __syncthreads();
    int b = tid >> 6, c = tid & 63;
    const float* wrr = Wr + c * 32;
    const float* cb  = ctx + b * 32;
    float acc = br[c];
    #pragma unroll
    for (int hv = 0; hv < 32; ++hv) acc += wrr[hv] * cb[hv];
    ws[WS_RC + b * NCH + c] = acc;
}

// ---------- out = x + rc[b][c]  (nontemporal stores: don't evict x) ----------
__global__ __launch_bounds__(256)
void ea3d_add(const float* __restrict__ x, const float* __restrict__ ws,
              float* __restrict__ out)
{
    const int row = blockIdx.y;                 // b*64 + c
    const float rc = ws[WS_RC + row];
    const size_t base = (size_t)row * NTOK;
    const float4*  xp = (const float4*)(x + base);
    floatx4*       op = (floatx4*)(out + base);
    const int nvec = NTOK / 4;
    for (int i = blockIdx.x * blockDim.x + threadIdx.x; i < nvec;
         i += gridDim.x * blockDim.x) {
        float4 v = xp[i];
        floatx4 nv = { v.x + rc, v.y + rc, v.z + rc, v.w + rc };
        __builtin_nontemporal_store(nv, op + i);
    }
}

extern "C" void kernel_launch(void* const* d_in, const int* in_sizes, int n_in,
                              void* d_out, int out_size, void* d_ws, size_t ws_size,
                              hipStream_t stream)
{
    const float* x  = (const float*)d_in[0];
    const float* Wk = (const float*)d_in[1];
    // d_in[2]=bk (cancels in token-softmax); d_in[3]=Wq, d_in[4]=bq (softmax over
    // size-1 head-channel axis -> identically 1.0, so Wq/bq are dead)
    const float* Wv = (const float*)d_in[5];
    const float* bv = (const float*)d_in[6];
    const float* Wr = (const float*)d_in[7];
    const float* br = (const float*)d_in[8];
    float* out = (float*)d_out;
    float* ws  = (float*)d_ws;

    (void)hipMemsetAsync(ws, 0, WS_RC * sizeof(float), stream);  // zero S + m accumulators
    ea3d_reduce<<<dim3(GRIDX, NB), TPB, 0, stream>>>(x, Wk, ws);
    ea3d_finalize<<<1, 256, 0, stream>>>(Wv, bv, Wr, br, ws);
    ea3d_add<<<dim3(32, NB * NCH), 256, 0, stream>>>(x, ws, out);
}